// Round 2
// baseline (422.053 us; speedup 1.0000x reference)
//
#include <hip/hip_runtime.h>
#include <hip/hip_bf16.h>
#include <stdint.h>

#define N_TOKENS 8192
#define IN_F 4096
#define OUT_F 4096

#define BM 128
#define BN 128
#define BK 64
#define KITERS (IN_F / BK)  // 64

typedef int int32x4 __attribute__((ext_vector_type(4)));

__device__ __forceinline__ void gload_lds16(const void* g, void* lds) {
  __builtin_amdgcn_global_load_lds(
      (const __attribute__((address_space(1))) void*)g,
      (__attribute__((address_space(3))) void*)lds, 16, 0, 0);
}

// ---- pack: int32 -> int8 for x and weight (one kernel, two ranges) ----
__global__ void pack_kernel(const int* __restrict__ x, const int* __restrict__ w,
                            signed char* __restrict__ xp, signed char* __restrict__ wp,
                            int n16x, int n16tot) {
  int gid = blockIdx.x * blockDim.x + threadIdx.x;
  if (gid >= n16tot) return;
  const int* src;
  signed char* dst;
  if (gid < n16x) {
    src = x + (size_t)gid * 16;
    dst = xp + (size_t)gid * 16;
  } else {
    int g2 = gid - n16x;
    src = w + (size_t)g2 * 16;
    dst = wp + (size_t)g2 * 16;
  }
  const int4* s4 = (const int4*)src;
  int o[4];
#pragma unroll
  for (int i = 0; i < 4; ++i) {
    int4 v = s4[i];
    o[i] = (v.x & 255) | ((v.y & 255) << 8) | ((v.z & 255) << 16) | (v.w << 24);
  }
  int4 pk;
  pk.x = o[0]; pk.y = o[1]; pk.z = o[2]; pk.w = o[3];
  *(int4*)dst = pk;
}

// ---- int8 MFMA GEMM: C = A @ B^T, requant epilogue ----
// A: [N_TOKENS][IN_F] i8 (packed x), B: [OUT_F][IN_F] i8 (packed weight)
__global__ __launch_bounds__(256) void gemm_i8(
    const signed char* __restrict__ A, const signed char* __restrict__ B,
    const int* __restrict__ bias, const float* __restrict__ wscale,
    int* __restrict__ out) {
  __shared__ signed char sA[BM * BK];  // 8 KB
  __shared__ signed char sB[BN * BK];  // 8 KB

  const int tid = threadIdx.x;
  const int lane = tid & 63;
  const int wid = tid >> 6;  // 0..3
  const int wr = wid >> 1;   // 0..1 (M-dir)
  const int wc = wid & 1;    // 0..1 (N-dir)

  const int brow = blockIdx.y * BM;
  const int bcol = blockIdx.x * BN;

  const int srow = tid >> 2;    // 0..63
  const int schunk = tid & 3;   // 16B chunk within 64B row

  int32x4 acc[4][4];
#pragma unroll
  for (int m = 0; m < 4; ++m)
#pragma unroll
    for (int n = 0; n < 4; ++n) acc[m][n] = (int32x4){0, 0, 0, 0};

  for (int kt = 0; kt < KITERS; ++kt) {
    const int k0 = kt * BK;
    // stage A,B tiles: LDS dest linear in tid (gload_lds requirement),
    // bank-conflict fix via pre-swizzled GLOBAL chunk (involution c^((row>>1)&3))
#pragma unroll
    for (int h = 0; h < 2; ++h) {
      int row = h * 64 + srow;
      int sc = schunk ^ ((row >> 1) & 3);
      gload_lds16(A + (size_t)(brow + row) * IN_F + k0 + sc * 16,
                  &sA[row * BK + schunk * 16]);
      gload_lds16(B + (size_t)(bcol + row) * IN_F + k0 + sc * 16,
                  &sB[row * BK + schunk * 16]);
    }
    __syncthreads();  // drains vmcnt -> LDS writes visible

    int32x4 af[4], bf[4];
#pragma unroll
    for (int m = 0; m < 4; ++m) {
      int row = wr * 64 + m * 16 + (lane & 15);
      int ch = (lane >> 4) ^ ((row >> 1) & 3);
      af[m] = *(const int32x4*)&sA[row * BK + ch * 16];
    }
#pragma unroll
    for (int n = 0; n < 4; ++n) {
      int row = wc * 64 + n * 16 + (lane & 15);
      int ch = (lane >> 4) ^ ((row >> 1) & 3);
      bf[n] = *(const int32x4*)&sB[row * BK + ch * 16];
    }
#pragma unroll
    for (int m = 0; m < 4; ++m)
#pragma unroll
      for (int n = 0; n < 4; ++n)
        acc[m][n] =
            __builtin_amdgcn_mfma_i32_16x16x64_i8(af[m], bf[n], acc[m][n], 0, 0, 0);
    __syncthreads();  // protect LDS before next stage
  }

  // epilogue: C/D layout col=lane&15, row=(lane>>4)*4+reg (dtype-independent, m121-128)
  // OUTPUT IS INT32 (harness promotes the reference's int8 output to int32).
  const int col_b = bcol + wc * 64 + (lane & 15);
  const int row_b = brow + wr * 64 + ((lane >> 4) << 2);
#pragma unroll
  for (int n = 0; n < 4; ++n) {
    int col = col_b + n * 16;
    float s = 0.02f * wscale[col] / 0.05f;
    int bz = bias[col];
#pragma unroll
    for (int m = 0; m < 4; ++m) {
      int row0 = row_b + m * 16;
#pragma unroll
      for (int r = 0; r < 4; ++r) {
        float f = (float)(acc[m][n][r] + bz) * s;
        f = rintf(f);                          // round-half-even == jnp.round
        f = fminf(127.f, fmaxf(-128.f, f));    // clip
        out[(size_t)(row0 + r) * OUT_F + col] = (int)f;
      }
    }
  }
}

extern "C" void kernel_launch(void* const* d_in, const int* in_sizes, int n_in,
                              void* d_out, int out_size, void* d_ws, size_t ws_size,
                              hipStream_t stream) {
  const int* x = (const int*)d_in[0];        // [8192,4096] values in [-128,127]
  const int* w = (const int*)d_in[1];        // [4096,4096]
  const int* bias = (const int*)d_in[2];     // [4096]
  const float* wsc = (const float*)d_in[3];  // [4096]
  int* out = (int*)d_out;

  signed char* xp = (signed char*)d_ws;                       // 32 MB
  signed char* wp = xp + (size_t)N_TOKENS * IN_F;             // 16 MB

  const int n16x = N_TOKENS * IN_F / 16;  // 2097152
  const int n16w = OUT_F * IN_F / 16;     // 1048576
  const int n16tot = n16x + n16w;         // 3145728

  pack_kernel<<<n16tot / 256, 256, 0, stream>>>(x, w, xp, wp, n16x, n16tot);

  dim3 grid(OUT_F / BN, N_TOKENS / BM);  // (32, 64) = 2048 blocks
  gemm_i8<<<grid, dim3(256), 0, stream>>>(xp, wp, bias, wsc, out);
}